// Round 6
// baseline (1525.165 us; speedup 1.0000x reference)
//
#include <hip/hip_runtime.h>

#define BB 512
#define TT 2048
#define II 8
#define HH 128
#define OO 96
#define PLANE 288            // bytes per A-plane (k=0..143 used; 288=18*16 keeps b128 align, staggers banks)
#define BUFB (4 * PLANE)     // 1152 B per buffer

typedef __attribute__((ext_vector_type(8))) short bf16x8;
typedef __attribute__((ext_vector_type(16))) float f32x16;

__device__ __forceinline__ float fast_rcp(float x) { return __builtin_amdgcn_rcpf(x); }
__device__ __forceinline__ float sigmoid_fast(float x) { return fast_rcp(1.0f + __expf(-x)); }
__device__ __forceinline__ float tanh_fast(float x) {
    return 1.0f - 2.0f * fast_rcp(1.0f + __expf(2.0f * x));
}
__device__ __forceinline__ unsigned short f2bf(float f) {
    unsigned int u = __builtin_bit_cast(unsigned int, f);
    u += 0x7fffu + ((u >> 16) & 1u);   // RNE
    return (unsigned short)(u >> 16);
}
__device__ __forceinline__ float bf2f(unsigned short h) {
    unsigned int u = ((unsigned int)h) << 16;
    return __builtin_bit_cast(float, u);
}

// Block = 4 waves (256 thr), 2 batch rows, full T scan. Wave wv owns j in [32wv, 32wv+32).
// MFMA 32x32x16 bf16, K_eff=144: k=[h(128) | x(8) | 1.0-bias-slot(1) | 0(7)].
// A rows m: plane m&3 = {b0hi, b0lo, b1hi, b1lo} (x8 duplicated).
// C/D (m101): col=lane&31, row=(reg&3)+8*(reg>>2)+4*(lane>>5) -> regs 0..3 = the 4 planes.
// gh(b0)+gx+bias = C[0]+C[1]; gh(b1) = C[2]+C[3]. Biases folded via k=136 slot.
__global__ __launch_bounds__(256, 1) void gru_kernel(
    const float* __restrict__ x,     // [B, T, I]
    const float* __restrict__ w_ih,  // [3H, I]
    const float* __restrict__ w_hh,  // [3H, H]
    const float* __restrict__ b_ih,  // [3H]
    const float* __restrict__ b_hh,  // [3H]
    const float* __restrict__ fc_w,  // [O, H]
    const float* __restrict__ fc_b,  // [O]
    float* __restrict__ out)         // [B, O]
{
    __shared__ __align__(16) char hbuf[2 * BUFB];
    __shared__ __align__(16) float hfin[2][HH];

    const int tid = threadIdx.x;
    const int wv  = tid >> 6;      // 0..3
    const int ln  = tid & 63;
    const int n32 = ln & 31;       // B n-index / C col
    const int kh  = ln >> 5;       // k-half (8 k's each)
    const int j   = 32 * wv + n32;
    const int b0  = blockIdx.x * 2;

    // ---- B fragments: B[k = kh*8 + i + 16c][n = j] = W[gate_row j][k] ----
    auto ld_hh = [&](int grow, int c) {
        const float* p = w_hh + grow * HH + c * 16 + kh * 8;
        float4 u = *(const float4*)(p);
        float4 v = *(const float4*)(p + 4);
        bf16x8 f;
        f[0] = (short)f2bf(u.x); f[1] = (short)f2bf(u.y);
        f[2] = (short)f2bf(u.z); f[3] = (short)f2bf(u.w);
        f[4] = (short)f2bf(v.x); f[5] = (short)f2bf(v.y);
        f[6] = (short)f2bf(v.z); f[7] = (short)f2bf(v.w);
        return f;
    };
    // tail chunk c=8 (k=128..143): kh0 -> x-weights (k'=0..7), kh1 -> bias at k'=8 (k=136)
    auto ld_tail = [&](const float* xw, float bias) {
        bf16x8 f = {0, 0, 0, 0, 0, 0, 0, 0};
        if (kh == 0) {
            if (xw) {
                float4 u = *(const float4*)(xw);
                float4 v = *(const float4*)(xw + 4);
                f[0] = (short)f2bf(u.x); f[1] = (short)f2bf(u.y);
                f[2] = (short)f2bf(u.z); f[3] = (short)f2bf(u.w);
                f[4] = (short)f2bf(v.x); f[5] = (short)f2bf(v.y);
                f[6] = (short)f2bf(v.z); f[7] = (short)f2bf(v.w);
            }
        } else {
            f[0] = (short)f2bf(bias);
        }
        return f;
    };

    bf16x8 bR[9], bZ[9], bN[9], bX;
#pragma unroll
    for (int c = 0; c < 8; ++c) {
        bR[c] = ld_hh(j, c);
        bZ[c] = ld_hh(HH + j, c);
        bN[c] = ld_hh(2 * HH + j, c);
    }
    bR[8] = ld_tail(w_ih + (size_t)j * II,            b_ih[j] + b_hh[j]);
    bZ[8] = ld_tail(w_ih + (size_t)(HH + j) * II,     b_ih[HH + j] + b_hh[HH + j]);
    bN[8] = ld_tail(nullptr,                          b_hh[2 * HH + j]);   // inside r*(.)
    bX    = ld_tail(w_ih + (size_t)(2 * HH + j) * II, b_ih[2 * HH + j]);   // outside

    // ---- zero both LDS buffers ----
    for (int i = tid; i < (2 * BUFB) / 4; i += 256) ((int*)hbuf)[i] = 0;
    __syncthreads();
    // bias slot k=136 (byte 272) = 1.0 in hi planes (0,2) of both buffers
    if (tid < 4) {
        char* pb = hbuf + (tid >> 1) * BUFB + ((tid & 1) * 2) * PLANE + 272;
        *(unsigned short*)pb = 0x3F80;
    }
    // x staging t=0: wave 0 lanes 0..15 (b = ln>>3, i = ln&7)
    const float* xr = x + (size_t)(b0 + (ln >> 3)) * TT * II + (ln & 7);
    float xc1 = 0.f, xc2 = 0.f;
    if (wv == 0 && ln < 16) {
        float x0 = xr[0];
        xc1 = xr[II];
        xc2 = xr[2 * II];
        unsigned short xh = f2bf(x0);
        char* xw = hbuf + ((ln >> 3) * 2) * PLANE + (128 + (ln & 7)) * 2;  // buf0 hi plane
        *(unsigned short*)(xw)         = xh;
        *(unsigned short*)(xw + PLANE) = f2bf(x0 - bf2f(xh));              // lo plane
    }
    __syncthreads();

    const char* abase = hbuf + (ln & 3) * PLANE + kh * 16;  // plane = A-row&3
    float h0 = 0.f, h1 = 0.f;
    const f32x16 zf = {0.f,0.f,0.f,0.f,0.f,0.f,0.f,0.f,0.f,0.f,0.f,0.f,0.f,0.f,0.f,0.f};

#define STEP(BUF, XVAL)                                                          \
    {                                                                            \
        const char* ab = abase + (BUF) * BUFB;                                   \
        bf16x8 a[9];                                                             \
        _Pragma("unroll")                                                        \
        for (int c = 0; c < 9; ++c) a[c] = *(const bf16x8*)(ab + c * 32);        \
        f32x16 cR = zf, cZ = zf, cN = zf;                                        \
        f32x16 cX = __builtin_amdgcn_mfma_f32_32x32x16_bf16(a[8], bX, zf, 0, 0, 0); \
        _Pragma("unroll")                                                        \
        for (int c = 0; c < 9; ++c) {                                            \
            cR = __builtin_amdgcn_mfma_f32_32x32x16_bf16(a[c], bR[c], cR, 0, 0, 0); \
            cZ = __builtin_amdgcn_mfma_f32_32x32x16_bf16(a[c], bZ[c], cZ, 0, 0, 0); \
            cN = __builtin_amdgcn_mfma_f32_32x32x16_bf16(a[c], bN[c], cN, 0, 0, 0); \
        }                                                                        \
        float gr0 = cR[0] + cR[1], gr1 = cR[2] + cR[3];                          \
        float gz0 = cZ[0] + cZ[1], gz1 = cZ[2] + cZ[3];                          \
        float gn0 = cN[0] + cN[1], gn1 = cN[2] + cN[3];                          \
        float gx0 = cX[0] + cX[1], gx1 = cX[2] + cX[3];                          \
        float r0 = sigmoid_fast(gr0), r1 = sigmoid_fast(gr1);                    \
        float z0 = sigmoid_fast(gz0), z1 = sigmoid_fast(gz1);                    \
        float n0 = tanh_fast(fmaf(r0, gn0, gx0));                                \
        float n1 = tanh_fast(fmaf(r1, gn1, gx1));                                \
        h0 = fmaf(z0, h0 - n0, n0);                                              \
        h1 = fmaf(z1, h1 - n1, n1);                                              \
        char* nb = hbuf + (1 - (BUF)) * BUFB;                                    \
        if (ln < 32) {                                                           \
            const int jj2 = (32 * wv + ln) * 2;                                  \
            unsigned short s0 = f2bf(h0), s1 = f2bf(h1);                         \
            *(unsigned short*)(nb + 0 * PLANE + jj2) = s0;                       \
            *(unsigned short*)(nb + 1 * PLANE + jj2) = f2bf(h0 - bf2f(s0));      \
            *(unsigned short*)(nb + 2 * PLANE + jj2) = s1;                       \
            *(unsigned short*)(nb + 3 * PLANE + jj2) = f2bf(h1 - bf2f(s1));      \
        }                                                                        \
        if (wv == 0 && ln < 16) {                                                \
            unsigned short xh = f2bf(XVAL);                                      \
            char* xw = nb + ((ln >> 3) * 2) * PLANE + (128 + (ln & 7)) * 2;      \
            *(unsigned short*)(xw)         = xh;                                 \
            *(unsigned short*)(xw + PLANE) = f2bf((XVAL) - bf2f(xh));            \
        }                                                                        \
        __syncthreads();                                                         \
    }

    for (int it = 0; it < TT / 2; ++it) {
        float xn1 = 0.f, xn2 = 0.f;
        if (wv == 0 && ln < 16) {                    // prefetch x(t+3), x(t+4)
            int t3 = 2 * it + 3; if (t3 >= TT) t3 = TT - 1;
            int t4 = 2 * it + 4; if (t4 >= TT) t4 = TT - 1;
            xn1 = xr[t3 * II];
            xn2 = xr[t4 * II];
        }
        STEP(0, xc1)    // even t: read buf0, write buf1
        STEP(1, xc2)    // odd  t: read buf1, write buf0
        xc1 = xn1; xc2 = xn2;
    }
#undef STEP

    // ---- epilogue FC ----
    if (ln < 32) {
        hfin[0][32 * wv + ln] = h0;
        hfin[1][32 * wv + ln] = h1;
    }
    __syncthreads();

    if (tid < 2 * OO) {
        const int bb2 = (tid >= OO) ? 1 : 0;
        const int o   = tid - OO * bb2;
        const float4* hf = (const float4*)(&hfin[bb2][0]);
        const float4* wp = (const float4*)(fc_w + o * HH);
        float acc = fc_b[o];
#pragma unroll 8
        for (int v = 0; v < HH / 4; ++v) {
            float4 w4 = wp[v];
            float4 h4 = hf[v];
            acc = fmaf(w4.x, h4.x, acc); acc = fmaf(w4.y, h4.y, acc);
            acc = fmaf(w4.z, h4.z, acc); acc = fmaf(w4.w, h4.w, acc);
        }
        out[(size_t)(b0 + bb2) * OO + o] = acc;
    }
}

extern "C" void kernel_launch(void* const* d_in, const int* in_sizes, int n_in,
                              void* d_out, int out_size, void* d_ws, size_t ws_size,
                              hipStream_t stream) {
    const float* x    = (const float*)d_in[0];
    const float* w_ih = (const float*)d_in[1];
    const float* w_hh = (const float*)d_in[2];
    const float* b_ih = (const float*)d_in[3];
    const float* b_hh = (const float*)d_in[4];
    const float* fc_w = (const float*)d_in[5];
    const float* fc_b = (const float*)d_in[6];
    float* out = (float*)d_out;

    gru_kernel<<<BB / 2, 256, 0, stream>>>(x, w_ih, w_hh, b_ih, b_hh, fc_w, fc_b, out);
}